// Round 19
// baseline (153.649 us; speedup 1.0000x reference)
//
#include <hip/hip_runtime.h>
#include <hip/hip_fp16.h>
#include <math.h>

#define PI_F      3.14159265358979323846f
#define TWO_PI_F  6.28318530717958647692f
#define PI4_F     0.78539816339744830962f   // pi/4 == ROT_SCALE == 2pi/8

typedef _Float16 f16x8  __attribute__((ext_vector_type(8)));
typedef float    f32x4  __attribute__((ext_vector_type(4)));
typedef float    f32x16 __attribute__((ext_vector_type(16)));

__device__ __forceinline__ float sgn(float t) {
    return (t > 0.f) ? 1.f : ((t < 0.f) ? -1.f : 0.f);
}

__device__ __forceinline__ float b2(float x) {
    float a = x - 0.5f;
    float b = x - 1.5f;
    float c = 1.f + 2.f * x;
    float d = 3.f + 2.f * x;
    return (-3.f * a * a * sgn(0.5f - x)
            + b * b * sgn(1.5f - x)
            - 0.75f * c * c * sgn(0.5f + x)
            + 0.25f * d * d * sgn(1.5f + x)) * 0.25f;
}

// ks_h[t][O][I] fp16.  t = dx*5+dy, O = r0*8+o, I = i*8+r
__global__ void build_ks_kernel(const float* __restrict__ w, __half* __restrict__ ksh) {
    int g = blockIdx.x * 256 + threadIdx.x;
    if (g >= 64 * 32 * 25) return;
    int O = g & 63;
    int rest = g >> 6;
    int t = rest % 25;
    int I = rest / 25;
    int r0 = O >> 3, o = O & 7;
    int i = I >> 3, r = I & 7;
    int x = t / 5, y = t % 5;

    float theta = -(float)r0 * PI4_F;
    float cth = cosf(theta), sth = sinf(theta);
    float fx = (float)(x - 2), fy = (float)(y - 2);
    float xc = fx * cth - fy * sth;
    float yc = fx * sth + fy * cth;

    float rotv[8];
    float rs = (float)r * PI4_F + theta;
    #pragma unroll
    for (int mr = 0; mr < 8; ++mr) {
        float v = (float)mr * PI4_F - rs + PI_F;
        float md = fmodf(v, TWO_PI_F);
        if (md < 0.f) md += TWO_PI_F;
        rotv[mr] = b2((md - PI_F) / PI4_F);
    }

    float sum = 0.f;
    for (int mx = 0; mx < 25; ++mx) {
        float cx = (float)(mx / 5 - 2);
        float cy = (float)(mx % 5 - 2);
        float bx = b2(cx - xc) * b2(cy - yc);
        if (bx != 0.f) {
            const float* wp = w + (size_t)(i * 200 + mx * 8) * 8 + o;
            #pragma unroll
            for (int mr = 0; mr < 8; ++mr)
                sum = fmaf(bx * rotv[mr], wp[mr * 8], sum);
        }
    }
    ksh[(size_t)(t * 64 + O) * 32 + I] = __float2half(sum);
}

// Single-pass fused implicit-GEMM conv, 32x32x16 MFMA, register-slim.
// Block = 256 threads (4 waves), tile 4h x 32w px, all 64 O.
//   wave = one output h-row (32 px = M) x 2 N-tiles (64 O): acc = 2 x f32x16
//   = 32 regs; 2 A ds_read_b128 + 4 MFMA per tap; 2-deep B prefetch ring.
// LDS xt[288 px (8x36 halo)][5 uint4] (80 B px stride -> 4-way banks, 23 KB)
//   -> 4 blocks/CU (92 KB LDS, ~110 unified regs -> 4 waves/SIMD).
// Stage fused: f32 CHW plane-gather -> cvt fp16 -> packed 64 B/px (no Xh
// pre-pass: X read exactly once; halo re-reads are L2/L3 hits).
// Fragment (A/B/store) lane mappings transplanted from the round-10
// verified 32x32 kernel. Grid 4096 blocks, b-major: 16 de-phased rounds/CU.
__global__ __launch_bounds__(256, 4) void conv_fused32_kernel(const float* __restrict__ X,
                                                              const __half* __restrict__ ksh,
                                                              float* __restrict__ out) {
    __shared__ uint4 xt[288 * 5];    // 23,040 B

    int bid = blockIdx.x;
    int b   = bid >> 9;              // 8 batches, b-major
    int rem = bid & 511;             // 512 tiles: 64 h-strips x 8 w-strips
    int h0  = (rem >> 3) << 2;       // 64 h-strips of 4
    int w0  = (rem & 7) << 5;        // 8 w-strips of 32
    int tid = threadIdx.x;

    const float* Xb = X + (size_t)b * 32 * 65536;

    // ---- fused stage: 288 px x 4 slots; slot = 8 channels ----
    for (int lin = tid; lin < 1152; lin += 256) {
        int px = lin >> 2, slot = lin & 3;
        int r = px / 36, c = px - (px / 36) * 36;
        int gh = h0 + r - 2;
        int gw = w0 + c - 2;
        union { __half hh[8]; uint4 u; } q;
        if ((unsigned)gh < 256u && (unsigned)gw < 256u) {
            const float* src = Xb + (size_t)slot * 8 * 65536 + gh * 256 + gw;
            #pragma unroll
            for (int j = 0; j < 8; ++j) q.hh[j] = __float2half(src[j * 65536]);
        } else {
            q.u = make_uint4(0u, 0u, 0u, 0u);
        }
        xt[px * 5 + slot] = q.u;
    }
    __syncthreads();

    int wave = tid >> 6, lane = tid & 63;
    int lM = lane & 31;              // A px-row / B col O / D col O
    int hi = lane >> 5;              // k-half within fragment
    const uint4* ksq = (const uint4*)ksh;
    int bB = lM * 4 + hi;            // B: + t*256 + n*128 + kh*2

    f32x16 acc[2] = {};              // [n]
    // A: px p = (wave + dx)*36 + lM + dy ; uint4 idx = p*5 + kh*2 + hi
    int aBase = (wave * 36 + lM) * 5 + hi;

    // ---- 2-deep B prefetch ring (static t%3 indices under full unroll) ----
    f16x8 Bf[3][2][2];               // [ring][n][kh]
    #pragma unroll
    for (int n = 0; n < 2; ++n) {
        #pragma unroll
        for (int kh = 0; kh < 2; ++kh) {
            Bf[0][n][kh] = __builtin_bit_cast(f16x8, ksq[0 * 256 + n * 128 + kh * 2 + bB]);
            Bf[1][n][kh] = __builtin_bit_cast(f16x8, ksq[1 * 256 + n * 128 + kh * 2 + bB]);
        }
    }

    #pragma unroll
    for (int t = 0; t < 25; ++t) {
        const int cur = t % 3;
        if (t < 23) {
            const int nn = (t + 2) % 3;
            #pragma unroll
            for (int n = 0; n < 2; ++n)
                #pragma unroll
                for (int kh = 0; kh < 2; ++kh)
                    Bf[nn][n][kh] = __builtin_bit_cast(f16x8,
                        ksq[(t + 2) * 256 + n * 128 + kh * 2 + bB]);
        }

        const int aoff = (t / 5) * 180 + (t % 5) * 5;
        f16x8 Af[2];
        Af[0] = __builtin_bit_cast(f16x8, xt[aBase + aoff]);       // kh = 0
        Af[1] = __builtin_bit_cast(f16x8, xt[aBase + aoff + 2]);   // kh = 1

        #pragma unroll
        for (int kh = 0; kh < 2; ++kh)
            #pragma unroll
            for (int n = 0; n < 2; ++n)
                acc[n] = __builtin_amdgcn_mfma_f32_32x32x16_f16(Af[kh], Bf[cur][n][kh], acc[n], 0, 0, 0);
    }

    // ---- store (round-10 verified D layout): col O = n*32+lM,
    //      w offset = (reg&3) + 8*(reg>>2) + 4*hi ----
    #pragma unroll
    for (int n = 0; n < 2; ++n) {
        int O = n * 32 + lM;
        float* plane = out + (((size_t)(b * 8 + (O & 7)) * 8 + (O >> 3)) << 16)
                           + (h0 + wave) * 256;
        #pragma unroll
        for (int g = 0; g < 4; ++g) {
            int wcol = w0 + g * 8 + hi * 4;
            f32x4 v;
            v.x = acc[n][4 * g + 0] * PI4_F;
            v.y = acc[n][4 * g + 1] * PI4_F;
            v.z = acc[n][4 * g + 2] * PI4_F;
            v.w = acc[n][4 * g + 3] * PI4_F;
            *(f32x4*)(plane + wcol) = v;
        }
    }
}

extern "C" void kernel_launch(void* const* d_in, const int* in_sizes, int n_in,
                              void* d_out, int out_size, void* d_ws, size_t ws_size,
                              hipStream_t stream) {
    const float* X = (const float*)d_in[0];       // (8, 4, 8, 256, 256) f32
    const float* w = (const float*)d_in[1];       // (4, 200, 8) f32
    float* outp = (float*)d_out;                  // (8, 8, 8, 256, 256) f32
    __half* ksh = (__half*)d_ws;                  // 102.4 KB

    build_ks_kernel<<<200, 256, 0, stream>>>(w, ksh);
    conv_fused32_kernel<<<8 * 512, 256, 0, stream>>>(X, ksh, outp);
}

// Round 20
// 100.315 us; speedup vs baseline: 1.5317x; 1.5317x over previous
//
#include <hip/hip_runtime.h>
#include <hip/hip_fp16.h>
#include <math.h>

#define PI_F      3.14159265358979323846f
#define TWO_PI_F  6.28318530717958647692f
#define PI4_F     0.78539816339744830962f   // pi/4 == ROT_SCALE == 2pi/8

typedef _Float16 f16x8 __attribute__((ext_vector_type(8)));
typedef float    f32x4 __attribute__((ext_vector_type(4)));

__device__ __forceinline__ float sgn(float t) {
    return (t > 0.f) ? 1.f : ((t < 0.f) ? -1.f : 0.f);
}

__device__ __forceinline__ float b2(float x) {
    float a = x - 0.5f;
    float b = x - 1.5f;
    float c = 1.f + 2.f * x;
    float d = 3.f + 2.f * x;
    return (-3.f * a * a * sgn(0.5f - x)
            + b * b * sgn(1.5f - x)
            - 0.75f * c * c * sgn(0.5f + x)
            + 0.25f * d * d * sgn(1.5f + x)) * 0.25f;
}

// ks_h[t][O][I] fp16.  t = dx*5+dy, O = r0*8+o, I = i*8+r
__global__ void build_ks_kernel(const float* __restrict__ w, __half* __restrict__ ksh) {
    int g = blockIdx.x * 256 + threadIdx.x;
    if (g >= 64 * 32 * 25) return;
    int O = g & 63;
    int rest = g >> 6;
    int t = rest % 25;
    int I = rest / 25;
    int r0 = O >> 3, o = O & 7;
    int i = I >> 3, r = I & 7;
    int x = t / 5, y = t % 5;

    float theta = -(float)r0 * PI4_F;
    float cth = cosf(theta), sth = sinf(theta);
    float fx = (float)(x - 2), fy = (float)(y - 2);
    float xc = fx * cth - fy * sth;
    float yc = fx * sth + fy * cth;

    float rotv[8];
    float rs = (float)r * PI4_F + theta;
    #pragma unroll
    for (int mr = 0; mr < 8; ++mr) {
        float v = (float)mr * PI4_F - rs + PI_F;
        float md = fmodf(v, TWO_PI_F);
        if (md < 0.f) md += TWO_PI_F;
        rotv[mr] = b2((md - PI_F) / PI4_F);
    }

    float sum = 0.f;
    for (int mx = 0; mx < 25; ++mx) {
        float cx = (float)(mx / 5 - 2);
        float cy = (float)(mx % 5 - 2);
        float bx = b2(cx - xc) * b2(cy - yc);
        if (bx != 0.f) {
            const float* wp = w + (size_t)(i * 200 + mx * 8) * 8 + o;
            #pragma unroll
            for (int mr = 0; mr < 8; ++mr)
                sum = fmaf(bx * rotv[mr], wp[mr * 8], sum);
        }
    }
    ksh[(size_t)(t * 64 + O) * 32 + I] = __float2half(sum);
}

// Single-pass fused implicit-GEMM conv (no Xh pre-pass).
// Block = 256 threads (4 waves), tile 8h x 32w px, all 64 O — the r18 conv
// structure (best measured: 77 us, 4 blocks/CU) with the f32->fp16 HWC
// transpose fused into the stage. Register budget: acc[4][4] = 64 AGPR +
// ~104 VGPR ≈ 168 unified -> __launch_bounds__(256,3): 3 co-resident
// blocks/CU (LDS 3 x 27.7 KB = 83 KB) keep the de-phased stage/MFMA/store
// overlap across blocks while deleting the 13 us hwc dispatch + Xh traffic.
// Operand-BW model (r19 post-mortem): A 256 B/MFMA from LDS + B 128-256 B
// from L1 caps MfmaUtil ~45-50% — conv floor ~45 us; this round removes
// serialization overhead, not loop cost.
__global__ __launch_bounds__(256, 3) void conv_fused_kernel(const float* __restrict__ X,
                                                            const __half* __restrict__ ksh,
                                                            float* __restrict__ out) {
    __shared__ uint4 xt[4 * 433];    // [slot 4][px 432 (12x36 halo)], 27,712 B

    int bid = blockIdx.x;
    int b   = bid >> 8;              // 8 batches, b-major
    int rem = bid & 255;             // 256 tiles/batch
    int h0  = (rem >> 3) << 3;       // 32 h-strips of 8
    int w0  = (rem & 7) << 5;        // 8 w-strips of 32
    int tid = threadIdx.x;

    const float* Xb = X + (size_t)b * 32 * 65536;

    // ---- fused stage: f32 CHW plane-gather -> cvt fp16 -> [slot][px] LDS ----
    for (int lin = tid; lin < 1728; lin += 256) {
        int slot = lin / 432;             // 0..3 (8 channels each)
        int p    = lin - slot * 432;      // 0..431
        int r = p / 36, c = p - (p / 36) * 36;
        int gh = h0 + r - 2;
        int gw = w0 + c - 2;
        union { __half hh[8]; uint4 u; } q;
        if ((unsigned)gh < 256u && (unsigned)gw < 256u) {
            const float* src = Xb + (size_t)slot * 8 * 65536 + gh * 256 + gw;
            #pragma unroll
            for (int j = 0; j < 8; ++j) q.hh[j] = __float2half(src[j * 65536]);
        } else {
            q.u = make_uint4(0u, 0u, 0u, 0u);
        }
        xt[slot * 433 + p] = q.u;
    }
    __syncthreads();

    int wave = tid >> 6, lane = tid & 63;
    int lO = lane & 15, ks4 = lane >> 4;
    int bidx = lO * 4 + ks4;
    const uint4* ksq = (const uint4*)ksh;

    f32x4 acc[4][4] = {};
    int baseA[4];
    #pragma unroll
    for (int m = 0; m < 4; ++m)
        baseA[m] = 433 * ks4 + (wave * 2 + (m >> 1)) * 36 + (m & 1) * 16 + lO;

    // ---- 25-tap loop: fresh A reads, 1-deep B prefetch double-buffer ----
    f16x8 Bf[2][4];
    #pragma unroll
    for (int n = 0; n < 4; ++n)
        Bf[0][n] = __builtin_bit_cast(f16x8, ksq[n * 64 + bidx]);

    #pragma unroll
    for (int t = 0; t < 25; ++t) {
        const int cur = t & 1, nxt = cur ^ 1;
        const int aoff = (t / 5) * 36 + (t % 5);

        f16x8 Af[4];
        #pragma unroll
        for (int m = 0; m < 4; ++m)
            Af[m] = __builtin_bit_cast(f16x8, xt[baseA[m] + aoff]);

        if (t < 24) {
            const int t1 = t + 1;
            #pragma unroll
            for (int n = 0; n < 4; ++n)
                Bf[nxt][n] = __builtin_bit_cast(f16x8, ksq[t1 * 256 + n * 64 + bidx]);
        }

        __builtin_amdgcn_s_setprio(1);
        #pragma unroll
        for (int m = 0; m < 4; ++m) {
            #pragma unroll
            for (int n = 0; n < 4; ++n)
                acc[m][n] = __builtin_amdgcn_mfma_f32_16x16x32_f16(Af[m], Bf[cur][n], acc[m][n], 0, 0, 0);
        }
        __builtin_amdgcn_s_setprio(0);
    }

    // ---- store: out[b][O&7][O>>3][h][w] * (2pi/8); full 128-B lines ----
    #pragma unroll
    for (int m = 0; m < 4; ++m) {
        int gh  = h0 + wave * 2 + (m >> 1);
        int gwb = w0 + (m & 1) * 16 + ks4 * 4;
        #pragma unroll
        for (int n = 0; n < 4; ++n) {
            int O = n * 16 + lO;
            float* op = out + (((size_t)(b * 8 + (O & 7)) * 8 + (O >> 3)) << 16)
                            + gh * 256 + gwb;
            *(f32x4*)op = acc[m][n] * PI4_F;
        }
    }
}

extern "C" void kernel_launch(void* const* d_in, const int* in_sizes, int n_in,
                              void* d_out, int out_size, void* d_ws, size_t ws_size,
                              hipStream_t stream) {
    const float* X = (const float*)d_in[0];       // (8, 4, 8, 256, 256) f32
    const float* w = (const float*)d_in[1];       // (4, 200, 8) f32
    float* outp = (float*)d_out;                  // (8, 8, 8, 256, 256) f32
    __half* ksh = (__half*)d_ws;                  // 102.4 KB

    build_ks_kernel<<<200, 256, 0, stream>>>(w, ksh);
    conv_fused_kernel<<<8 * 256, 256, 0, stream>>>(X, ksh, outp);
}